// Round 6
// baseline (305.841 us; speedup 1.0000x reference)
//
#include <hip/hip_runtime.h>
#include <cstdint>

// ShortTermLSTM on MI355X: batched LSTM, transposed-GEMM f16 MFMA, cell fully
// in registers, fused-rcp activations in the exp2 domain (raw v_exp_f32).
// R15 251 steady. R16 269 / R17 262 / R18 256: no pipe saturated ->
// latency-bound at 2 waves/SIMD. R19 256 flat: VGPR 64 but AGPR 72 ->
// total 136 > 128 -> 64-reg granule rounds to 192 -> STILL 2 waves/SIMD
// (compiler's launch_bounds models arch VGPRs only, not unified file).
// VALU model: VALUBusy 53% x 258us = 137us/SIMD busy, trans-dominated
// (7 exp/rcp per cell = floor). Lever = occupancy.
// R20 (this): cross the 128 boundary WITH MARGIN: offload 4 frags/wave
// (kc3 of B-tiles x3 + kc3 of pair2 A-tile) to LDS s_W3 (16KB).
//   wfrag 72 -> 56 AGPR; target total ~120 <= 128 -> 4 waves/SIMD capacity.
//   LDS 53,760 B -> 3 blocks/CU -> ALL 768 blocks resident, zero tail,
//   3 independent blocks/CU hide each other's dependency chains.
// Pair-tile layout (tile<24): tileA rows {i(u0),i(u1),f(u0),f(u1)} x4 quads,
// tileB {g,g,o,o}; u0 = 8*pair + 2*quad, u1 = u0+1. Lane acc:
// accA=(i0,i1,f0,f1), accB=(g0,g1,o0,o1) -> v_pk_*_f32 activation; one
// ds_write_b32 per pair. k-map identity for h (k=u); x/bias k100..113.
// Residual error: dropped h*W_hh_lo (~6e-5/step); measured margin ~4x.

#define H_UNITS 100
#define T_STEPS 128
#define S_BLK   16
#define NSEQ    12288
#define NBLK    (NSEQ / S_BLK)   // 768
#define NTILE   25               // 100 units / 4 rows-of-4 per tile
#define KSTR    136              // LDS h row stride (ushorts)
#define LOG2E   1.4426950408889634f
#define TWO_L   2.8853900817779268f   // 2*log2(e)

typedef __attribute__((ext_vector_type(8))) _Float16 halfx8;
typedef __attribute__((ext_vector_type(8))) unsigned short ushortx8;
typedef __attribute__((ext_vector_type(4))) float floatx4;
typedef __attribute__((ext_vector_type(2))) float floatx2;

__device__ __forceinline__ unsigned short f32_to_f16u(float x) {
    _Float16 h = (_Float16)x;                       // v_cvt_f16_f32 (RNE)
    return __builtin_bit_cast(unsigned short, h);
}
__device__ __forceinline__ float f16u_to_f32(unsigned short u) {
    _Float16 h = __builtin_bit_cast(_Float16, u);
    return (float)h;
}
#if __has_builtin(__builtin_amdgcn_exp2f)
__device__ __forceinline__ float fexp2(float x) { return __builtin_amdgcn_exp2f(x); }
#else
__device__ __forceinline__ float fexp2(float x) { return exp2f(x); }
#endif

// ---------------------------------------------------------------------------
// Prep: pack W (pre-scaled into exp2 domain) into MFMA A-operand fragments.
// Pair-tile row map (tile<24): pr=tile>>1, half=tile&1, reg=m&3, qr=m>>2:
//   gate = (reg>>1) + 2*half   (A: i,f ; B: g,o)
//   unit = 8*pr + 2*qr + (reg&1)
//   n = gate*100 + unit        (torch gate order i,f,g,o)
// Tile 24: n = (m&3)*100 + 96 + (m>>2)  (i,f,g,o-per-quad layout).
// k-map: identity for h (k<100); x/bias cols:
//   k100..103 x_hi(W_hi); k104..107 x_lo(W_hi); k108..111 x_hi(W_lo);
//   k112/113 bias hi/lo (A=1.0); k114..127 zero.
// ---------------------------------------------------------------------------
__global__ void lstm_prep_pack(const float* __restrict__ W_ih,
                               const float* __restrict__ W_hh,
                               const float* __restrict__ b_ih,
                               const float* __restrict__ b_hh,
                               ushortx8* __restrict__ Bpack) {
    int t = blockIdx.x * 256 + threadIdx.x;   // (tile,kc,lane): 25*4*64 = 6400
    if (t >= NTILE * 4 * 64) return;
    int lane = t & 63;
    int kc   = (t >> 6) & 3;
    int tile = t >> 8;
    int m    = lane & 15;
    int n;
    if (tile < 24) {
        int pr = tile >> 1, half = tile & 1;
        int reg = m & 3,   qr   = m >> 2;
        int g = (reg >> 1) + 2 * half;
        int u = 8 * pr + 2 * qr + (reg & 1);
        n = g * 100 + u;
    } else {
        n = (m & 3) * 100 + 96 + (m >> 2);
    }
    float sc = (n >= 200 && n < 300) ? (2.0f * LOG2E) : LOG2E;   // g rows get 2x
    int k0 = kc * 32 + ((lane >> 4) & 3) * 8;
    ushortx8 v;
#pragma unroll
    for (int j = 0; j < 8; ++j) {
        int k = k0 + j;
        unsigned short w = 0;
        if (k < 100) {
            w = f32_to_f16u(W_hh[n * 100 + k] * sc);             // identity k-map
        } else if (k < 108) {
            w = f32_to_f16u(W_ih[n * 4 + ((k - 100) & 3)] * sc); // hi W (x_hi & x_lo)
        } else if (k < 112) {
            float wf = W_ih[n * 4 + (k - 108)] * sc;             // lo W (x_hi)
            unsigned short hi = f32_to_f16u(wf);
            w = f32_to_f16u(wf - f16u_to_f32(hi));
        } else if (k == 112) {
            float bb = (b_ih[n] + b_hh[n]) * sc;                 // b_hi (A=1.0)
            w = f32_to_f16u(bb);
        } else if (k == 113) {
            float bb = (b_ih[n] + b_hh[n]) * sc;                 // b_lo (A=1.0)
            unsigned short hi = f32_to_f16u(bb);
            w = f32_to_f16u(bb - f16u_to_f32(hi));
        }
        v[j] = w;
    }
    Bpack[t] = v;
}

// ---------------------------------------------------------------------------
// Main: one block = 16 sequences, full T loop. 4 waves; wave w owns pairs
// {w, w+4, w+8} (tiles 2p,2p+1); wave0 additionally tile 24 (W from LDS).
// AGPR wfrag = 14 frags (56 regs): A-tiles of pairs 0,1 keep kc1..3;
// pair-2 A-tile and all B-tiles keep kc1..2; their kc3 lives in s_W3 (LDS).
// kc0 (all tiles) in s_W; tile24 kc1..3 in s_W24. One barrier per step.
// Target total (V+A)GPR ~120 <= 128 -> 4 waves/SIMD; LDS 53,760 B -> 3
// blocks/CU -> all 768 blocks resident.
// ---------------------------------------------------------------------------
__global__ void __launch_bounds__(256, 4)
lstm_main(const float* __restrict__ x, const ushortx8* __restrict__ Bpack,
          float* __restrict__ out) {
    __shared__ __align__(16) unsigned short s_A[2][16 * KSTR];   // ping-pong, 8,704 B
    __shared__ __align__(16) ushortx8       s_W[NTILE * 64];     // 25,600 B, kc0 frags
    __shared__ __align__(16) ushortx8       s_W24[3 * 64];       //  3,072 B, tile24 kc1..3
    __shared__ __align__(16) ushortx8       s_W3[4 * 4 * 64];    // 16,384 B, offloaded kc3

    const int tid  = threadIdx.x;
    const int lane = tid & 63;
    const int wavu = __builtin_amdgcn_readfirstlane(tid >> 6);   // wave id in SGPR
    const int seq0 = blockIdx.x * S_BLK;
    const int m    = lane & 15;
    const int quad = lane >> 4;
    const int q2   = quad << 1;

    // ---- W fragments in AGPRs: 14 frags = 56 regs
    halfx8 wfA01[2][3];   // pairs 0,1 A-tiles, kc1..3
    halfx8 wfA2[2];       // pair 2  A-tile,  kc1..2 (kc3 in s_W3)
    halfx8 wfB[3][2];     // B-tiles,         kc1..2 (kc3 in s_W3)
#pragma unroll
    for (int it = 0; it < 2; ++it) {
        int tile = 2 * (wavu + it * 4);
#pragma unroll
        for (int kc = 0; kc < 3; ++kc)
            wfA01[it][kc] = __builtin_bit_cast(halfx8, Bpack[(tile * 4 + kc + 1) * 64 + lane]);
    }
    {
        int tile = 2 * (wavu + 8);
#pragma unroll
        for (int kc = 0; kc < 2; ++kc)
            wfA2[kc] = __builtin_bit_cast(halfx8, Bpack[(tile * 4 + kc + 1) * 64 + lane]);
    }
#pragma unroll
    for (int it = 0; it < 3; ++it) {
        int tile = 2 * (wavu + it * 4) + 1;
#pragma unroll
        for (int kc = 0; kc < 2; ++kc)
            wfB[it][kc] = __builtin_bit_cast(halfx8, Bpack[(tile * 4 + kc + 1) * 64 + lane]);
    }

    // ---- LDS weight staging: kc0 (all tiles), tile24 kc1..3, offloaded kc3
    for (int i = tid; i < NTILE * 64; i += 256)
        s_W[i] = Bpack[(i >> 6) * 256 + (i & 63)];
    if (tid < 3 * 64)
        s_W24[tid] = Bpack[(24 * 4 + 1 + (tid >> 6)) * 64 + (tid & 63)];
    // s_W3 entry (w, f, lane): f=0..2 -> B-tile kc3 of pair f; f=3 -> A-tile
    // kc3 of pair 2 (for wave w).
    for (int i = tid; i < 4 * 4 * 64; i += 256) {
        int w = i >> 8, f = (i >> 6) & 3, ln = i & 63;
        int tile = (f < 3) ? (2 * (w + f * 4) + 1) : (2 * (w + 8));
        s_W3[i] = Bpack[(tile * 4 + 3) * 64 + ln];
    }

    // refresh-thread x pointer (valid for tid >= 128): (s = rt&15, cc = rt>>4)
    const int rt = tid - 128;
    const int rs = rt & 15, rc = (rt >> 4) & 7;
    const float* xb = x + (size_t)(seq0 + rs) * (T_STEPS * 4) + (rc & 3);

    // ---- zero both buffers (h(0)=0; k114..127 stay 0 forever)
    for (int i = tid; i < (2 * 16 * KSTR) / 2; i += 256)
        ((unsigned int*)s_A)[i] = 0u;
    float x0 = 0.0f;
    if (tid >= 128) x0 = xb[0];
    __syncthreads();
    // ---- x(t=0) into buf0; constant bias-select cols into BOTH buffers
    if (tid >= 128) {
        unsigned short hi = f32_to_f16u(x0);
        if (rc < 4) {
            s_A[0][rs * KSTR + 100 + rc] = hi;                    // x_hi (W_hi)
            s_A[0][rs * KSTR + 108 + rc] = hi;                    // x_hi (W_lo)
        } else {
            s_A[0][rs * KSTR + 104 + (rc - 4)] =
                f32_to_f16u(x0 - f16u_to_f32(hi));                // x_lo (W_hi)
        }
    } else if (tid < 32) {
        s_A[tid >> 4][(tid & 15) * KSTR + 112] = 0x3C00;   // k112 = 1.0, both bufs
    } else if (tid < 64) {
        int d = tid - 32;
        s_A[d >> 4][(d & 15) * KSTR + 113] = 0x3C00;       // k113 = 1.0, both bufs
    }
    __syncthreads();   // init writes visible before first read

    floatx2 cpr[3];   // cell state pairs (u0,u1) per owned pair, 2*log2e domain
#pragma unroll
    for (int it = 0; it < 3; ++it) cpr[it] = (floatx2){0.0f, 0.0f};
    float c24 = 0.0f;

    const int rowOff = m * KSTR;
    const int aOff   = rowOff + quad * 8;
    const int w3base = wavu * 256 + lane;    // s_W3 base (loop-invariant)

    for (int t = 0; t < T_STEPS; ++t) {
        const int bR = t & 1;
        const unsigned short* base  = s_A[bR];
        unsigned short*       baseW = s_A[bR ^ 1];

        // prefetch x(t+1) — issued before compute phase to hide latency
        float xnext = 0.0f;
        if (tid >= 128) {
            int tn = t + 1; if (tn > T_STEPS - 1) tn = T_STEPS - 1;
            xnext = xb[tn * 4];
        }

        halfx8 hh[4];
#pragma unroll
        for (int kc = 0; kc < 4; ++kc)
            hh[kc] = *(const halfx8*)(base + aOff + kc * 32);   // ds_read_b128

        const bool last = (t == T_STEPS - 1);

        auto gemm4 = [&](halfx8 w0, halfx8 w1, halfx8 w2, halfx8 w3) {
            floatx4 a = {0.0f, 0.0f, 0.0f, 0.0f};
            a = __builtin_amdgcn_mfma_f32_16x16x32_f16(w0, hh[0], a, 0, 0, 0);
            a = __builtin_amdgcn_mfma_f32_16x16x32_f16(w1, hh[1], a, 0, 0, 0);
            a = __builtin_amdgcn_mfma_f32_16x16x32_f16(w2, hh[2], a, 0, 0, 0);
            a = __builtin_amdgcn_mfma_f32_16x16x32_f16(w3, hh[3], a, 0, 0, 0);
            return a;
        };

        // packed 2-cell activation: accA=(i0,i1,f0,f1), accB=(g0,g1,o0,o1)
        auto activatePair = [&](floatx4 aA, floatx4 aB, floatx2& cm, int p) {
            floatx2 ei = {fexp2(aA[0]), fexp2(aA[1])};   // e^i
            floatx2 ef = {fexp2(aA[2]), fexp2(aA[3])};   // e^f
            floatx2 eg = {fexp2(aB[0]), fexp2(aB[1])};   // e^{2g}
            floatx2 eo = {fexp2(aB[2]), fexp2(aB[3])};   // e^o
            floatx2 a  = ei + 1.0f;                      // v_pk_add_f32
            floatx2 b  = ef + 1.0f;
            floatx2 d  = eg + 1.0f;
            floatx2 p1 = eo + 1.0f;
            floatx2 e2s = eg * TWO_L - TWO_L;            // v_pk_fma_f32
            floatx2 q  = a * d;
            floatx2 qb = q * b;
            floatx2 r  = {__builtin_amdgcn_rcpf(qb[0]), __builtin_amdgcn_rcpf(qb[1])};
            floatx2 eib = ei * b;
            floatx2 efq = ef * q;
            floatx2 tt  = eib * e2s;
            floatx2 nm  = efq * cm + tt;                 // v_pk_fma_f32
            floatx2 c2  = nm * r;
            cm = c2;
            floatx2 cc = {fminf(c2[0], 115.0f), fminf(c2[1], 115.0f)};
            floatx2 ec = {fexp2(cc[0]), fexp2(cc[1])};   // e^{2c}
            floatx2 p2 = ec + 1.0f;
            floatx2 nu = ec - 1.0f;
            floatx2 pp = p1 * p2;
            floatx2 r2 = {__builtin_amdgcn_rcpf(pp[0]), __builtin_amdgcn_rcpf(pp[1])};
            floatx2 eon = eo * nu;
            floatx2 hv  = eon * r2;
            if (!last) {
                unsigned int pk = (unsigned int)f32_to_f16u(hv[0]) |
                                  ((unsigned int)f32_to_f16u(hv[1]) << 16);
                *(unsigned int*)&baseW[rowOff + 8 * p + q2] = pk;   // ds_write_b32
            } else {
                *(floatx2*)&out[(size_t)(seq0 + m) * H_UNITS + 8 * p + q2] = hv;
            }
        };

#pragma unroll
        for (int it = 0; it < 3; ++it) {                 // 3 pairs per wave
            int p = wavu + it * 4;
            halfx8 w0A = __builtin_bit_cast(halfx8, s_W[(2 * p) * 64 + lane]);
            halfx8 w0B = __builtin_bit_cast(halfx8, s_W[(2 * p + 1) * 64 + lane]);
            halfx8 w3B = __builtin_bit_cast(halfx8, s_W3[w3base + it * 64]);
            floatx4 aA, aB;
            if (it < 2) {
                aA = gemm4(w0A, wfA01[it][0], wfA01[it][1], wfA01[it][2]);
            } else {
                halfx8 w3A = __builtin_bit_cast(halfx8, s_W3[w3base + 3 * 64]);
                aA = gemm4(w0A, wfA2[0], wfA2[1], w3A);
            }
            aB = gemm4(w0B, wfB[it][0], wfB[it][1], w3B);
            activatePair(aA, aB, cpr[it], p);
        }

        if (wavu == 0) {   // tile 24 (units 96..99): scalar path, W from LDS
            halfx8 w0 = __builtin_bit_cast(halfx8, s_W[24 * 64 + lane]);
            halfx8 w1 = __builtin_bit_cast(halfx8, s_W24[0 * 64 + lane]);
            halfx8 w2 = __builtin_bit_cast(halfx8, s_W24[1 * 64 + lane]);
            halfx8 w3 = __builtin_bit_cast(halfx8, s_W24[2 * 64 + lane]);
            floatx4 acc = gemm4(w0, w1, w2, w3);
            float ei = fexp2(acc[0]);
            float ef = fexp2(acc[1]);
            float eg = fexp2(acc[2]);
            float eo = fexp2(acc[3]);
            float a  = 1.0f + ei, b = 1.0f + ef;
            float d  = eg + 1.0f;
            float e2s = fmaf(eg, TWO_L, -TWO_L);
            float q  = a * d;
            float r  = __builtin_amdgcn_rcpf(q * b);
            float nm = fmaf(ef * q, c24, (ei * b) * e2s);
            float c2 = nm * r;
            c24 = c2;
            float cc = fminf(c2, 115.0f);
            float ec = fexp2(cc);
            float r2 = __builtin_amdgcn_rcpf((1.0f + eo) * (ec + 1.0f));
            float h  = (eo * (ec - 1.0f)) * r2;
            if (!last) {
                baseW[rowOff + 96 + quad] = f32_to_f16u(h);        // k = unit
            } else {
                out[(size_t)(seq0 + m) * H_UNITS + 96 + quad] = h;
            }
        }

        if (tid >= 128 && !last) {               // x(t+1) -> other buffer
            unsigned short hi = f32_to_f16u(xnext);
            if (rc < 4) {
                baseW[rs * KSTR + 100 + rc] = hi;
                baseW[rs * KSTR + 108 + rc] = hi;
            } else {
                baseW[rs * KSTR + 104 + (rc - 4)] =
                    f32_to_f16u(xnext - f16u_to_f32(hi));
            }
        }
        __syncthreads();   // single barrier/step: covers both cross-step hazards
    }
}

extern "C" void kernel_launch(void* const* d_in, const int* in_sizes, int n_in,
                              void* d_out, int out_size, void* d_ws, size_t ws_size,
                              hipStream_t stream) {
    const float* x    = (const float*)d_in[0];   // [4096,3,128,4]
    const float* W_ih = (const float*)d_in[1];   // [400,4]
    const float* W_hh = (const float*)d_in[2];   // [400,100]
    const float* b_ih = (const float*)d_in[3];   // [400]
    const float* b_hh = (const float*)d_in[4];   // [400]
    ushortx8* Bpack = (ushortx8*)d_ws;           // 25*4*64*16 B = 102,400 B

    lstm_prep_pack<<<25, 256, 0, stream>>>(W_ih, W_hh, b_ih, b_hh, Bpack);
    lstm_main<<<NBLK, 256, 0, stream>>>(x, Bpack, (float*)d_out);
}

// Round 8
// 284.445 us; speedup vs baseline: 1.0752x; 1.0752x over previous
//
#include <hip/hip_runtime.h>
#include <cstdint>

// ShortTermLSTM on MI355X: batched LSTM, transposed-GEMM f16 MFMA, cell fully
// in registers, fused-rcp activations in the exp2 domain (raw v_exp_f32).
// R15 251 best. R16-R20 falsified topology/schedule/knife-edge-reg levers.
// Allocation model (over-determined by R15/R19/R20): unified (V+A)GPR total
// rounds to {64,128,192,256}; >128 => 2 waves/SIMD. MFMA accumulators count.
// 4-wave blocks need ~6 tiles W/wave -> total ~135-160 -> stuck at 2 w/SIMD.
// R21 (resubmit; prior round was an infra container failure, kernel unrun):
// 8-WAVE blocks (512 thr, 16 seqs) to halve per-wave state:
//   wave w: own pair (tiles 2w,2w+1) all-kc in regs = 8 frags = 32 AGPR.
//   waves 0-3: + pair 8+w with W from LDS (8 ds_reads/step).
//   wave 4: + tile 24 from LDS. waves 5-6: x-refresh. wave 7: light.
//   Target total ~105 <= 128 -> 4 waves/SIMD -> 16 waves/CU (2 blocks).
//   LDS 45,568 B (s_A 8.7K + tiles16..24 all-kc 36.9K).
//   __launch_bounds__(512,4) pins the 128-reg budget.
// Pair-tile layout (tile<24): tileA rows {i(u0),i(u1),f(u0),f(u1)} x4 quads,
// tileB {g,g,o,o}; u0 = 8*pair + 2*quad, u1 = u0+1. Lane acc:
// accA=(i0,i1,f0,f1), accB=(g0,g1,o0,o1) -> v_pk_*_f32 activation; one
// ds_write_b32 per pair. k-map identity for h (k=u); x/bias k100..113.
// Residual error: dropped h*W_hh_lo (~6e-5/step); measured margin ~4x.

#define H_UNITS 100
#define T_STEPS 128
#define S_BLK   16
#define NSEQ    12288
#define NBLK    (NSEQ / S_BLK)   // 768
#define NTILE   25               // 100 units / 4 rows-of-4 per tile
#define KSTR    136              // LDS h row stride (ushorts)
#define LOG2E   1.4426950408889634f
#define TWO_L   2.8853900817779268f   // 2*log2(e)

typedef __attribute__((ext_vector_type(8))) _Float16 halfx8;
typedef __attribute__((ext_vector_type(8))) unsigned short ushortx8;
typedef __attribute__((ext_vector_type(4))) float floatx4;
typedef __attribute__((ext_vector_type(2))) float floatx2;

__device__ __forceinline__ unsigned short f32_to_f16u(float x) {
    _Float16 h = (_Float16)x;                       // v_cvt_f16_f32 (RNE)
    return __builtin_bit_cast(unsigned short, h);
}
__device__ __forceinline__ float f16u_to_f32(unsigned short u) {
    _Float16 h = __builtin_bit_cast(_Float16, u);
    return (float)h;
}
#if __has_builtin(__builtin_amdgcn_exp2f)
__device__ __forceinline__ float fexp2(float x) { return __builtin_amdgcn_exp2f(x); }
#else
__device__ __forceinline__ float fexp2(float x) { return exp2f(x); }
#endif

// ---------------------------------------------------------------------------
// Prep: pack W (pre-scaled into exp2 domain) into MFMA A-operand fragments.
// Pair-tile row map (tile<24): pr=tile>>1, half=tile&1, reg=m&3, qr=m>>2:
//   gate = (reg>>1) + 2*half   (A: i,f ; B: g,o)
//   unit = 8*pr + 2*qr + (reg&1)
//   n = gate*100 + unit        (torch gate order i,f,g,o)
// Tile 24: n = (m&3)*100 + 96 + (m>>2)  (i,f,g,o-per-quad layout).
// k-map: identity for h (k<100); x/bias cols:
//   k100..103 x_hi(W_hi); k104..107 x_lo(W_hi); k108..111 x_hi(W_lo);
//   k112/113 bias hi/lo (A=1.0); k114..127 zero.
// ---------------------------------------------------------------------------
__global__ void lstm_prep_pack(const float* __restrict__ W_ih,
                               const float* __restrict__ W_hh,
                               const float* __restrict__ b_ih,
                               const float* __restrict__ b_hh,
                               ushortx8* __restrict__ Bpack) {
    int t = blockIdx.x * 256 + threadIdx.x;   // (tile,kc,lane): 25*4*64 = 6400
    if (t >= NTILE * 4 * 64) return;
    int lane = t & 63;
    int kc   = (t >> 6) & 3;
    int tile = t >> 8;
    int m    = lane & 15;
    int n;
    if (tile < 24) {
        int pr = tile >> 1, half = tile & 1;
        int reg = m & 3,   qr   = m >> 2;
        int g = (reg >> 1) + 2 * half;
        int u = 8 * pr + 2 * qr + (reg & 1);
        n = g * 100 + u;
    } else {
        n = (m & 3) * 100 + 96 + (m >> 2);
    }
    float sc = (n >= 200 && n < 300) ? (2.0f * LOG2E) : LOG2E;   // g rows get 2x
    int k0 = kc * 32 + ((lane >> 4) & 3) * 8;
    ushortx8 v;
#pragma unroll
    for (int j = 0; j < 8; ++j) {
        int k = k0 + j;
        unsigned short w = 0;
        if (k < 100) {
            w = f32_to_f16u(W_hh[n * 100 + k] * sc);             // identity k-map
        } else if (k < 108) {
            w = f32_to_f16u(W_ih[n * 4 + ((k - 100) & 3)] * sc); // hi W (x_hi & x_lo)
        } else if (k < 112) {
            float wf = W_ih[n * 4 + (k - 108)] * sc;             // lo W (x_hi)
            unsigned short hi = f32_to_f16u(wf);
            w = f32_to_f16u(wf - f16u_to_f32(hi));
        } else if (k == 112) {
            float bb = (b_ih[n] + b_hh[n]) * sc;                 // b_hi (A=1.0)
            w = f32_to_f16u(bb);
        } else if (k == 113) {
            float bb = (b_ih[n] + b_hh[n]) * sc;                 // b_lo (A=1.0)
            unsigned short hi = f32_to_f16u(bb);
            w = f32_to_f16u(bb - f16u_to_f32(hi));
        }
        v[j] = w;
    }
    Bpack[t] = v;
}

// ---------------------------------------------------------------------------
// Main: one block = 16 sequences, 8 waves, full T loop.
// Wave w: own pair p0=w (tiles 2w,2w+1, all kc in regs).
//   w<4 : second pair p1=8+w (tiles 16+2w,17+2w) with W from s_W.
//   w==4: tile 24 (units 96..99) with W from s_W.
//   w in {5,6}: x-refresh threads (tids 320..447).
// s_W frag f: f<32 -> tile 16+(f>>2), kc=f&3 ; f in 32..35 -> tile24 kc=f-32.
// One barrier per step.
// ---------------------------------------------------------------------------
__global__ void __launch_bounds__(512, 4)
lstm_main(const float* __restrict__ x, const ushortx8* __restrict__ Bpack,
          float* __restrict__ out) {
    __shared__ __align__(16) unsigned short s_A[2][16 * KSTR];   // ping-pong, 8,704 B
    __shared__ __align__(16) ushortx8       s_W[36 * 64];        // 36,864 B

    const int tid  = threadIdx.x;
    const int lane = tid & 63;
    const int wavu = __builtin_amdgcn_readfirstlane(tid >> 6);   // 0..7
    const int seq0 = blockIdx.x * S_BLK;
    const int m    = lane & 15;
    const int quad = lane >> 4;
    const int q2   = quad << 1;

    // ---- own-pair W fragments, all kc in regs (8 frags = 32 regs)
    halfx8 wfA[4], wfB[4];
#pragma unroll
    for (int kc = 0; kc < 4; ++kc) {
        wfA[kc] = __builtin_bit_cast(halfx8, Bpack[((2 * wavu) * 4 + kc) * 64 + lane]);
        wfB[kc] = __builtin_bit_cast(halfx8, Bpack[((2 * wavu + 1) * 4 + kc) * 64 + lane]);
    }

    // ---- LDS weight staging: tiles 16..23 (all kc) + tile 24 (all kc)
    for (int i = tid; i < 36 * 64; i += 512) {
        int f = i >> 6, ln = i & 63;
        int tile = (f < 32) ? (16 + (f >> 2)) : 24;
        int kc   = (f < 32) ? (f & 3) : (f - 32);
        s_W[i] = Bpack[(tile * 4 + kc) * 64 + ln];
    }

    // refresh-thread x pointer (valid for tid in [320,448)): 16 seqs x 8 cols
    const int rt   = tid - 320;
    const bool refr = (rt >= 0) && (rt < 128);
    const int rtc  = refr ? rt : 0;
    const int rs   = rtc & 15, rc = (rtc >> 4) & 7;
    const float* xb = x + (size_t)(seq0 + rs) * (T_STEPS * 4) + (rc & 3);

    // ---- zero both buffers (h(0)=0; k114..127 stay 0 forever)
    for (int i = tid; i < (2 * 16 * KSTR) / 2; i += 512)
        ((unsigned int*)s_A)[i] = 0u;
    float x0 = 0.0f;
    if (refr) x0 = xb[0];
    __syncthreads();
    // ---- x(t=0) into buf0; constant bias-select cols into BOTH buffers
    if (refr) {
        unsigned short hi = f32_to_f16u(x0);
        if (rc < 4) {
            s_A[0][rs * KSTR + 100 + rc] = hi;                    // x_hi (W_hi)
            s_A[0][rs * KSTR + 108 + rc] = hi;                    // x_hi (W_lo)
        } else {
            s_A[0][rs * KSTR + 104 + (rc - 4)] =
                f32_to_f16u(x0 - f16u_to_f32(hi));                // x_lo (W_hi)
        }
    } else if (tid < 64) {
        // 64 writes: 2 bufs x 16 rows x 2 bias cols (k112,k113) = 1.0
        int b = tid >> 5, r = (tid >> 1) & 15, col = 112 + (tid & 1);
        s_A[b][r * KSTR + col] = 0x3C00;
    }
    __syncthreads();   // init + s_W visible before first read

    floatx2 c0 = {0.0f, 0.0f};    // own pair cell state (2*log2e domain)
    floatx2 c1 = {0.0f, 0.0f};    // second pair (waves 0..3)
    float   c24 = 0.0f;           // tile 24 (wave 4)

    const int rowOff = m * KSTR;
    const int aOff   = rowOff + quad * 8;
    const int hb     = wavu * 512 + lane;    // s_W heavy-pair base (A at +0, B at +256)

    for (int t = 0; t < T_STEPS; ++t) {
        const int bR = t & 1;
        const unsigned short* base  = s_A[bR];
        unsigned short*       baseW = s_A[bR ^ 1];

        // prefetch x(t+1) — issued before compute phase to hide latency
        float xnext = 0.0f;
        if (refr) {
            int tn = t + 1; if (tn > T_STEPS - 1) tn = T_STEPS - 1;
            xnext = xb[tn * 4];
        }

        halfx8 hh[4];
#pragma unroll
        for (int kc = 0; kc < 4; ++kc)
            hh[kc] = *(const halfx8*)(base + aOff + kc * 32);   // ds_read_b128

        const bool last = (t == T_STEPS - 1);

        auto gemm4 = [&](halfx8 w0, halfx8 w1, halfx8 w2, halfx8 w3) {
            floatx4 a = {0.0f, 0.0f, 0.0f, 0.0f};
            a = __builtin_amdgcn_mfma_f32_16x16x32_f16(w0, hh[0], a, 0, 0, 0);
            a = __builtin_amdgcn_mfma_f32_16x16x32_f16(w1, hh[1], a, 0, 0, 0);
            a = __builtin_amdgcn_mfma_f32_16x16x32_f16(w2, hh[2], a, 0, 0, 0);
            a = __builtin_amdgcn_mfma_f32_16x16x32_f16(w3, hh[3], a, 0, 0, 0);
            return a;
        };

        // packed 2-cell activation: accA=(i0,i1,f0,f1), accB=(g0,g1,o0,o1)
        auto activatePair = [&](floatx4 aA, floatx4 aB, floatx2& cm, int p) {
            floatx2 ei = {fexp2(aA[0]), fexp2(aA[1])};   // e^i
            floatx2 ef = {fexp2(aA[2]), fexp2(aA[3])};   // e^f
            floatx2 eg = {fexp2(aB[0]), fexp2(aB[1])};   // e^{2g}
            floatx2 eo = {fexp2(aB[2]), fexp2(aB[3])};   // e^o
            floatx2 a  = ei + 1.0f;                      // v_pk_add_f32
            floatx2 b  = ef + 1.0f;
            floatx2 d  = eg + 1.0f;
            floatx2 p1 = eo + 1.0f;
            floatx2 e2s = eg * TWO_L - TWO_L;            // v_pk_fma_f32
            floatx2 q  = a * d;
            floatx2 qb = q * b;
            floatx2 r  = {__builtin_amdgcn_rcpf(qb[0]), __builtin_amdgcn_rcpf(qb[1])};
            floatx2 eib = ei * b;
            floatx2 efq = ef * q;
            floatx2 tt  = eib * e2s;
            floatx2 nm  = efq * cm + tt;                 // v_pk_fma_f32
            floatx2 c2  = nm * r;
            cm = c2;
            floatx2 cc = {fminf(c2[0], 115.0f), fminf(c2[1], 115.0f)};
            floatx2 ec = {fexp2(cc[0]), fexp2(cc[1])};   // e^{2c}
            floatx2 p2 = ec + 1.0f;
            floatx2 nu = ec - 1.0f;
            floatx2 pp = p1 * p2;
            floatx2 r2 = {__builtin_amdgcn_rcpf(pp[0]), __builtin_amdgcn_rcpf(pp[1])};
            floatx2 eon = eo * nu;
            floatx2 hv  = eon * r2;
            if (!last) {
                unsigned int pk = (unsigned int)f32_to_f16u(hv[0]) |
                                  ((unsigned int)f32_to_f16u(hv[1]) << 16);
                *(unsigned int*)&baseW[rowOff + 8 * p + q2] = pk;   // ds_write_b32
            } else {
                *(floatx2*)&out[(size_t)(seq0 + m) * H_UNITS + 8 * p + q2] = hv;
            }
        };

        // ---- own pair (W in regs)
        {
            floatx4 aA = gemm4(wfA[0], wfA[1], wfA[2], wfA[3]);
            floatx4 aB = gemm4(wfB[0], wfB[1], wfB[2], wfB[3]);
            activatePair(aA, aB, c0, wavu);
        }

        if (wavu < 4) {
            // ---- second pair p1 = 8+wavu (tiles 16+2w / 17+2w), W from LDS
            halfx8 wa0 = __builtin_bit_cast(halfx8, s_W[hb + 0 * 64]);
            halfx8 wa1 = __builtin_bit_cast(halfx8, s_W[hb + 1 * 64]);
            halfx8 wa2 = __builtin_bit_cast(halfx8, s_W[hb + 2 * 64]);
            halfx8 wa3 = __builtin_bit_cast(halfx8, s_W[hb + 3 * 64]);
            floatx4 aA = gemm4(wa0, wa1, wa2, wa3);
            halfx8 wb0 = __builtin_bit_cast(halfx8, s_W[hb + 256 + 0 * 64]);
            halfx8 wb1 = __builtin_bit_cast(halfx8, s_W[hb + 256 + 1 * 64]);
            halfx8 wb2 = __builtin_bit_cast(halfx8, s_W[hb + 256 + 2 * 64]);
            halfx8 wb3 = __builtin_bit_cast(halfx8, s_W[hb + 256 + 3 * 64]);
            floatx4 aB = gemm4(wb0, wb1, wb2, wb3);
            activatePair(aA, aB, c1, 8 + wavu);
        } else if (wavu == 4) {
            // ---- tile 24 (units 96..99), W from LDS, scalar activation
            halfx8 w0 = __builtin_bit_cast(halfx8, s_W[2048 + 0 * 64 + lane]);
            halfx8 w1 = __builtin_bit_cast(halfx8, s_W[2048 + 1 * 64 + lane]);
            halfx8 w2 = __builtin_bit_cast(halfx8, s_W[2048 + 2 * 64 + lane]);
            halfx8 w3 = __builtin_bit_cast(halfx8, s_W[2048 + 3 * 64 + lane]);
            floatx4 acc = gemm4(w0, w1, w2, w3);
            float ei = fexp2(acc[0]);
            float ef = fexp2(acc[1]);
            float eg = fexp2(acc[2]);
            float eo = fexp2(acc[3]);
            float a  = 1.0f + ei, b = 1.0f + ef;
            float d  = eg + 1.0f;
            float e2s = fmaf(eg, TWO_L, -TWO_L);
            float q  = a * d;
            float r  = __builtin_amdgcn_rcpf(q * b);
            float nm = fmaf(ef * q, c24, (ei * b) * e2s);
            float c2 = nm * r;
            c24 = c2;
            float cc = fminf(c2, 115.0f);
            float ec = fexp2(cc);
            float r2 = __builtin_amdgcn_rcpf((1.0f + eo) * (ec + 1.0f));
            float h  = (eo * (ec - 1.0f)) * r2;
            if (!last) {
                baseW[rowOff + 96 + quad] = f32_to_f16u(h);        // k = unit
            } else {
                out[(size_t)(seq0 + m) * H_UNITS + 96 + quad] = h;
            }
        }

        if (refr && !last) {                     // x(t+1) -> other buffer
            unsigned short hi = f32_to_f16u(xnext);
            if (rc < 4) {
                baseW[rs * KSTR + 100 + rc] = hi;
                baseW[rs * KSTR + 108 + rc] = hi;
            } else {
                baseW[rs * KSTR + 104 + (rc - 4)] =
                    f32_to_f16u(xnext - f16u_to_f32(hi));
            }
        }
        __syncthreads();   // single barrier/step: covers both cross-step hazards
    }
}

extern "C" void kernel_launch(void* const* d_in, const int* in_sizes, int n_in,
                              void* d_out, int out_size, void* d_ws, size_t ws_size,
                              hipStream_t stream) {
    const float* x    = (const float*)d_in[0];   // [4096,3,128,4]
    const float* W_ih = (const float*)d_in[1];   // [400,4]
    const float* W_hh = (const float*)d_in[2];   // [400,100]
    const float* b_ih = (const float*)d_in[3];   // [400]
    const float* b_hh = (const float*)d_in[4];   // [400]
    ushortx8* Bpack = (ushortx8*)d_ws;           // 25*4*64*16 B = 102,400 B

    lstm_prep_pack<<<25, 256, 0, stream>>>(W_ih, W_hh, b_ih, b_hh, Bpack);
    lstm_main<<<NBLK, 512, 0, stream>>>(x, Bpack, (float*)d_out);
}